// Round 1
// 878.571 us; speedup vs baseline: 1.2296x; 1.2296x over previous
//
#include <hip/hip_runtime.h>

typedef unsigned short u16;
typedef u16 u16x8 __attribute__((ext_vector_type(8)));
typedef u16 u16x4 __attribute__((ext_vector_type(4)));
typedef short s16x8 __attribute__((ext_vector_type(8)));
typedef float f32x4 __attribute__((ext_vector_type(4)));

__device__ __forceinline__ float b2f(u16 u) {
  unsigned int v = ((unsigned int)u) << 16;
  return __builtin_bit_cast(float, v);
}
__device__ __forceinline__ u16 f2b(float f) {
  unsigned int u = __builtin_bit_cast(unsigned int, f);
  u += 0x7FFFu + ((u >> 16) & 1u);
  return (u16)(u >> 16);
}

// ---------------- graph prep ----------------
__global__ void deg_kernel(const int* __restrict__ dst, int* __restrict__ deg, int E, int n) {
  int e = blockIdx.x * 256 + threadIdx.x;
  if (e < E) {
    int d = dst[e];
    d = min(max(d, 0), n - 1);
    atomicAdd(&deg[d], 1);
  }
}

__global__ void dis_kernel(const int* __restrict__ deg, float* __restrict__ dis, int n) {
  int i = blockIdx.x * 256 + threadIdx.x;
  if (i < n) dis[i] = 1.0f / sqrtf((float)(deg[i] + 1));  // +1 self-loop
}

// 3-phase exclusive scan of deg -> rowp
__global__ __launch_bounds__(256) void scanA(const int* __restrict__ cnt, int* __restrict__ bsum, int n) {
  __shared__ int s[256];
  int t = threadIdx.x, i = blockIdx.x * 256 + t;
  s[t] = (i < n) ? cnt[i] : 0;
  __syncthreads();
  for (int off = 128; off > 0; off >>= 1) {
    if (t < off) s[t] += s[t + off];
    __syncthreads();
  }
  if (t == 0) bsum[blockIdx.x] = s[0];
}

__global__ __launch_bounds__(256) void scanB(int* __restrict__ bsum, int nb) {
  __shared__ int s[256];
  int t = threadIdx.x;
  int v = (t < nb) ? bsum[t] : 0;
  s[t] = v;
  __syncthreads();
  for (int off = 1; off < 256; off <<= 1) {
    int x = (t >= off) ? s[t - off] : 0;
    __syncthreads();
    s[t] += x;
    __syncthreads();
  }
  if (t < nb) bsum[t] = s[t] - v;  // exclusive
}

__global__ __launch_bounds__(256) void scanC(const int* __restrict__ cnt, const int* __restrict__ bsum,
                                             int* __restrict__ rowp, int n) {
  __shared__ int s[256];
  int t = threadIdx.x, i = blockIdx.x * 256 + t;
  int v = (i < n) ? cnt[i] : 0;
  s[t] = v;
  __syncthreads();
  for (int off = 1; off < 256; off <<= 1) {
    int x = (t >= off) ? s[t - off] : 0;
    __syncthreads();
    s[t] += x;
    __syncthreads();
  }
  if (i < n) rowp[i + 1] = bsum[blockIdx.x] + s[t];
  if (i == 0) rowp[0] = 0;
}

__global__ void fill_kernel(const int* __restrict__ src, const int* __restrict__ dst,
                            const int* __restrict__ rowp, int* __restrict__ fill,
                            const float* __restrict__ dis, int* __restrict__ csr_s,
                            float* __restrict__ csr_w, int E, int n) {
  int e = blockIdx.x * 256 + threadIdx.x;
  if (e < E) {
    int s = src[e]; s = min(max(s, 0), n - 1);
    int d = dst[e]; d = min(max(d, 0), n - 1);
    int pos = rowp[d] + atomicAdd(&fill[d], 1);
    csr_s[pos] = s;
    csr_w[pos] = dis[s] * dis[d];
  }
}

// transpose + f32->bf16 convert: in [K,N] f32 row-major -> out [N,K] bf16
__global__ void transpose_cvt(const float* __restrict__ in, u16* __restrict__ out, int K, int N) {
  int idx = blockIdx.x * 256 + threadIdx.x;
  if (idx < K * N) {
    int k = idx / N, nn = idx - k * N;
    out[(size_t)nn * K + k] = f2b(in[idx]);
  }
}

// ---------------- MFMA GEMM: C[M,N] = A[M,K] @ BT[N,K]^T (+bias) ----------------
// 128x128 tile, 4 waves each 64x64 (4x4 of 16x16x32 mfma). LDS rows padded to 40 shorts.
// Double-buffered, reg-staged software pipeline: tile t+1's global loads are issued
// BEFORE tile t's ds_read+MFMA; the vmcnt wait + convert + ds_write happen after the
// MFMAs; one barrier per k-iter. (Previous version was latency-bound: all pipes <10%.)
template <bool A_F32, bool OUT_F32>
__global__ __launch_bounds__(256) void gemm_kernel(const void* __restrict__ Ap,
                                                   const u16* __restrict__ BT,
                                                   const float* __restrict__ bias,
                                                   void* __restrict__ Cp, int M, int N, int K) {
  __shared__ u16 As[2][128 * 40];
  __shared__ u16 Bs[2][128 * 40];
  const int tid = threadIdx.x;
  const int m0 = blockIdx.y * 128, n0 = blockIdx.x * 128;
  const int lane = tid & 63, wv = tid >> 6;
  const int wr = (wv >> 1) * 64, wc = (wv & 1) * 64;
  const int q = lane >> 4, l = lane & 15;
  f32x4 acc[4][4] = {};

  // per-thread staging registers (in-flight tile t+1)
  float4 aregf[4];  // A_F32 path: 128 rows x 8 chunks of 4 floats
  u16x8 aregb[2];   // bf16 path: 128 rows x 4 chunks of 8 bf16
  u16x8 breg[2];

  auto load_tile = [&](int kt) {
    if (A_F32) {
      const float* A = (const float*)Ap;
#pragma unroll
      for (int i = 0; i < 4; i++) {
        int t = tid + i * 256;
        int r = t >> 3, k4 = (t & 7) * 4;
        int gr = m0 + r;
        aregf[i] = make_float4(0.f, 0.f, 0.f, 0.f);
        if (gr < M) aregf[i] = *(const float4*)&A[(size_t)gr * K + kt + k4];
      }
    } else {
      const u16* A = (const u16*)Ap;
#pragma unroll
      for (int i = 0; i < 2; i++) {
        int t = tid + i * 256;
        int r = t >> 2, k8 = (t & 3) * 8;
        int gr = m0 + r;
        aregb[i] = (u16x8){};
        if (gr < M) aregb[i] = *(const u16x8*)&A[(size_t)gr * K + kt + k8];
      }
    }
#pragma unroll
    for (int i = 0; i < 2; i++) {
      int t = tid + i * 256;
      int r = t >> 2, k8 = (t & 3) * 8;
      breg[i] = *(const u16x8*)&BT[(size_t)(n0 + r) * K + kt + k8];
    }
  };

  auto store_tile = [&](int buf) {
    if (A_F32) {
#pragma unroll
      for (int i = 0; i < 4; i++) {
        int t = tid + i * 256;
        int r = t >> 3, k4 = (t & 7) * 4;
        u16x4 o;
        o[0] = f2b(aregf[i].x); o[1] = f2b(aregf[i].y);
        o[2] = f2b(aregf[i].z); o[3] = f2b(aregf[i].w);
        *(u16x4*)&As[buf][r * 40 + k4] = o;
      }
    } else {
#pragma unroll
      for (int i = 0; i < 2; i++) {
        int t = tid + i * 256;
        int r = t >> 2, k8 = (t & 3) * 8;
        *(u16x8*)&As[buf][r * 40 + k8] = aregb[i];
      }
    }
#pragma unroll
    for (int i = 0; i < 2; i++) {
      int t = tid + i * 256;
      int r = t >> 2, k8 = (t & 3) * 8;
      *(u16x8*)&Bs[buf][r * 40 + k8] = breg[i];
    }
  };

  // prologue: stage tile 0
  load_tile(0);
  store_tile(0);
  __syncthreads();

  int cur = 0;
  for (int kt = 0; kt < K; kt += 32) {
    const bool has_next = (kt + 32) < K;
    if (has_next) load_tile(kt + 32);  // issue global loads early (vmcnt pending)

    s16x8 af[4], bf[4];
#pragma unroll
    for (int mi = 0; mi < 4; mi++) af[mi] = *(const s16x8*)&As[cur][(wr + mi * 16 + l) * 40 + q * 8];
#pragma unroll
    for (int ni = 0; ni < 4; ni++) bf[ni] = *(const s16x8*)&Bs[cur][(wc + ni * 16 + l) * 40 + q * 8];
#pragma unroll
    for (int mi = 0; mi < 4; mi++)
#pragma unroll
      for (int ni = 0; ni < 4; ni++)
        acc[mi][ni] = __builtin_amdgcn_mfma_f32_16x16x32_bf16(af[mi], bf[ni], acc[mi][ni], 0, 0, 0);

    if (has_next) store_tile(cur ^ 1);  // vmcnt wait lands here, under/after the MFMAs
    __syncthreads();
    cur ^= 1;
  }

#pragma unroll
  for (int ni = 0; ni < 4; ni++) {
    int col = n0 + wc + ni * 16 + l;
    float bv = bias ? bias[col] : 0.f;
#pragma unroll
    for (int mi = 0; mi < 4; mi++) {
#pragma unroll
      for (int j = 0; j < 4; j++) {
        int row = m0 + wr + mi * 16 + q * 4 + j;
        if (row < M) {
          float v = acc[mi][ni][j] + bv;
          if (OUT_F32)
            ((float*)Cp)[(size_t)row * N + col] = v;
          else
            ((u16*)Cp)[(size_t)row * N + col] = f2b(v);
        }
      }
    }
  }
}

// ---------------- CSR aggregation over 256 bf16 features, one wave per node ----------------
// Edge loop unrolled 4x: issue 4 independent index loads, then 4 independent 512B
// gathers, then FMAs — breaks the serial load->gather->fma chain (~600cy/edge).
template <bool RELU>
__global__ __launch_bounds__(256) void agg_kernel(const u16* __restrict__ tab,
                                                  const int* __restrict__ rowp,
                                                  const int* __restrict__ csr_s,
                                                  const float* __restrict__ csr_w,
                                                  const float* __restrict__ dis,
                                                  const float* __restrict__ bias,
                                                  u16* __restrict__ out, int n) {
  int wv = threadIdx.x >> 6, lane = threadIdx.x & 63;
  int node = blockIdx.x * 4 + wv;
  if (node >= n) return;
  int f0 = lane * 4;
  float sw = dis[node];
  sw *= sw;  // self-loop weight = 1/deg
  u16x4 v = *(const u16x4*)&tab[(size_t)node * 256 + f0];
  float a0 = sw * b2f(v[0]), a1 = sw * b2f(v[1]), a2 = sw * b2f(v[2]), a3 = sw * b2f(v[3]);
  int e0 = rowp[node], e1 = rowp[node + 1];
  int e = e0;
  for (; e + 4 <= e1; e += 4) {
    int s0 = csr_s[e], s1 = csr_s[e + 1], s2 = csr_s[e + 2], s3 = csr_s[e + 3];
    float w0 = csr_w[e], w1 = csr_w[e + 1], w2 = csr_w[e + 2], w3 = csr_w[e + 3];
    u16x4 u0 = *(const u16x4*)&tab[(size_t)s0 * 256 + f0];
    u16x4 u1 = *(const u16x4*)&tab[(size_t)s1 * 256 + f0];
    u16x4 u2 = *(const u16x4*)&tab[(size_t)s2 * 256 + f0];
    u16x4 u3 = *(const u16x4*)&tab[(size_t)s3 * 256 + f0];
    a0 += w0 * b2f(u0[0]) + w1 * b2f(u1[0]) + w2 * b2f(u2[0]) + w3 * b2f(u3[0]);
    a1 += w0 * b2f(u0[1]) + w1 * b2f(u1[1]) + w2 * b2f(u2[1]) + w3 * b2f(u3[1]);
    a2 += w0 * b2f(u0[2]) + w1 * b2f(u1[2]) + w2 * b2f(u2[2]) + w3 * b2f(u3[2]);
    a3 += w0 * b2f(u0[3]) + w1 * b2f(u1[3]) + w2 * b2f(u2[3]) + w3 * b2f(u3[3]);
  }
  for (; e < e1; e++) {
    int s = csr_s[e];
    float w = csr_w[e];
    u16x4 u = *(const u16x4*)&tab[(size_t)s * 256 + f0];
    a0 += w * b2f(u[0]);
    a1 += w * b2f(u[1]);
    a2 += w * b2f(u[2]);
    a3 += w * b2f(u[3]);
  }
  if (RELU) {
    a0 = fmaxf(a0 + bias[f0 + 0], 0.f);
    a1 = fmaxf(a1 + bias[f0 + 1], 0.f);
    a2 = fmaxf(a2 + bias[f0 + 2], 0.f);
    a3 = fmaxf(a3 + bias[f0 + 3], 0.f);
  }
  u16x4 o;
  o[0] = f2b(a0); o[1] = f2b(a1); o[2] = f2b(a2); o[3] = f2b(a3);
  *(u16x4*)&out[(size_t)node * 256 + f0] = o;
}

extern "C" void kernel_launch(void* const* d_in, const int* in_sizes, int n_in,
                              void* d_out, int out_size, void* d_ws, size_t ws_size,
                              hipStream_t stream) {
  const float* x  = (const float*)d_in[0];
  const int*   ei = (const int*)d_in[1];
  const float* W1 = (const float*)d_in[2];
  const float* b1 = (const float*)d_in[3];
  const float* W2 = (const float*)d_in[4];
  const float* b2 = (const float*)d_in[5];

  const int MID = in_sizes[3];            // 256
  const int IN  = in_sizes[5];            // 1024
  const int n   = in_sizes[0] / IN;       // 50000
  const int E   = in_sizes[1] / 2;        // 1600000
  const int* srcv = ei;
  const int* dstv = ei + E;

  char* w = (char*)d_ws;
  size_t off = 0;
  auto alloc = [&](size_t bytes) -> void* {
    void* p = w + off;
    off += (bytes + 255) & ~(size_t)255;
    return p;
  };
  int*   deg   = (int*)alloc((size_t)n * 4);
  int*   rowp  = (int*)alloc((size_t)(n + 1) * 4);
  int*   fill  = (int*)alloc((size_t)n * 4);
  int*   bsum  = (int*)alloc(1024);
  int*   csr_s = (int*)alloc((size_t)E * 4);
  float* csr_w = (float*)alloc((size_t)E * 4);
  float* dis   = (float*)alloc((size_t)n * 4);
  u16*   W1T   = (u16*)alloc((size_t)IN * MID * 2);
  u16*   W2T   = (u16*)alloc((size_t)IN * MID * 2);
  u16*   xw    = (u16*)alloc((size_t)n * MID * 2);
  u16*   h     = (u16*)alloc((size_t)n * MID * 2);
  u16*   ah    = xw;  // xw dead after agg1; reuse for agg2 output

  hipMemsetAsync(deg, 0, (size_t)n * 4, stream);
  hipMemsetAsync(fill, 0, (size_t)n * 4, stream);

  transpose_cvt<<<(IN * MID + 255) / 256, 256, 0, stream>>>(W1, W1T, IN, MID);
  transpose_cvt<<<(IN * MID + 255) / 256, 256, 0, stream>>>(W2, W2T, MID, IN);

  const int nb = (n + 255) / 256;  // 196 <= 256
  deg_kernel<<<(E + 255) / 256, 256, 0, stream>>>(dstv, deg, E, n);
  dis_kernel<<<nb, 256, 0, stream>>>(deg, dis, n);
  scanA<<<nb, 256, 0, stream>>>(deg, bsum, n);
  scanB<<<1, 256, 0, stream>>>(bsum, nb);
  scanC<<<nb, 256, 0, stream>>>(deg, bsum, rowp, n);
  fill_kernel<<<(E + 255) / 256, 256, 0, stream>>>(srcv, dstv, rowp, fill, dis, csr_s, csr_w, E, n);

  // xw = bf16(x) @ W1   [n, MID] bf16
  dim3 g1(MID / 128, (n + 127) / 128);
  gemm_kernel<true, false><<<g1, 256, 0, stream>>>(x, W1T, nullptr, xw, n, MID, IN);
  // h = relu(A @ xw + b1)   bf16
  agg_kernel<true><<<(n + 3) / 4, 256, 0, stream>>>(xw, rowp, csr_s, csr_w, dis, b1, h, n);
  // ah = A @ h   bf16
  agg_kernel<false><<<(n + 3) / 4, 256, 0, stream>>>(h, rowp, csr_s, csr_w, dis, nullptr, ah, n);
  // out = ah @ W2 + b2   [n, IN] f32
  dim3 g2(IN / 128, (n + 127) / 128);
  gemm_kernel<false, true><<<g2, 256, 0, stream>>>(ah, W2T, b2, d_out, n, IN, MID);
}